// Round 6
// baseline (162.095 us; speedup 1.0000x reference)
//
#include <hip/hip_runtime.h>
#include <stdint.h>

#define BB 64
#define LL 512
#define DD 300
#define CC 128

// ws layout (floats):
//   Gred4 : [64][4][3][300] = 230,400  (4 atomic accumulation slices per b)
//   hT    : [64][384]       =  24,576  (b-major so k_fc reads coalesce)
//   skbk  : [8]  (Sk[0..2], bk[0..2])
#define OFF_HT   (BB * 4 * 3 * DD)
#define OFF_SKBK (OFF_HT + BB * 3 * CC)

// ---------------------------------------------------------------------------
// Kernel 1: weighted embedding gather, atomic 4-slice accumulation.
//   Gred4[b][tc&3][kk][d] += sum_{t in chunk tc} u_k[t]*embed[x[b,t]][d]
// u_k[t] = sum of wk[l] over valid windows covering token t (<=5 terms).
// Grid 2048+3 blocks x 256: blocks <2048 gather (8 blocks/CU = 32 waves/CU,
// max TLP to hide the L3-resident random-row load latency); 16 tokens per
// block, 8 per half-block; thread owns float2 slots {stid, 128+stid(<150)}.
// Blocks 2048..2050 compute Sk[kk] = sum(wk) and stash bk[kk].
// Gred4 must be zeroed beforehand (memset node).
// ---------------------------------------------------------------------------
__global__ __launch_bounds__(256) void k_gather(
    const int* __restrict__ x, const float* __restrict__ embed,
    const float* __restrict__ w3, const float* __restrict__ b3,
    const float* __restrict__ w4, const float* __restrict__ b4,
    const float* __restrict__ w5, const float* __restrict__ b5,
    float* __restrict__ Gred4, float* __restrict__ skbk) {
  const int blk = blockIdx.x;
  const int tid = threadIdx.x;

  if (blk >= 2048) {  // Sk / bk blocks
    __shared__ float red[256];
    const int kk = blk - 2048;
    const float* wk = (kk == 0) ? w3 : ((kk == 1) ? w4 : w5);
    const float* bk = (kk == 0) ? b3 : ((kk == 1) ? b4 : b5);
    const int len = LL - (kk + 3);
    float s = (tid < len) ? wk[tid] : 0.f;
    if (tid + 256 < len) s += wk[tid + 256];
    red[tid] = s;
    __syncthreads();
    for (int off = 128; off >= 1; off >>= 1) {
      if (tid < off) red[tid] += red[tid + off];
      __syncthreads();
    }
    if (tid == 0) { skbk[kk] = red[0]; skbk[3 + kk] = bk[0]; }
    return;
  }

  const int b = blk >> 5;     // 0..63
  const int tc = blk & 31;    // 0..31 (chunk of 16 tokens)
  const int sub = tid >> 7;   // half-block: 8 tokens each
  const int stid = tid & 127; // float2 slot

  __shared__ int sx[16];
  __shared__ float su[3][16];

  if (tid < 16) {
    const int t = tc * 16 + tid;
    sx[tid] = x[b * LL + t];
    const float* ws[3] = {w3, w4, w5};
#pragma unroll
    for (int kk = 0; kk < 3; ++kk) {
      const int k = kk + 3;
      int lo = t - k + 1; if (lo < 0) lo = 0;
      int hi = t; const int lim = LL - k - 1; if (hi > lim) hi = lim;
      float s = 0.f;
      for (int l = lo; l <= hi; ++l) s += ws[kk][l];
      su[kk][tid] = s;
    }
  }
  __syncthreads();

  float a0x = 0.f, a0y = 0.f, a1x = 0.f, a1y = 0.f, a2x = 0.f, a2y = 0.f;
  float c0x = 0.f, c0y = 0.f, c1x = 0.f, c1y = 0.f, c2x = 0.f, c2y = 0.f;
  const bool tail = stid < (DD / 2 - 128);  // slots 128..149 -> 22 lanes

#pragma unroll
  for (int i = 0; i < 8; ++i) {
    const int j = sub * 8 + i;
    const float2* rp = (const float2*)(embed + (size_t)sx[j] * DD);
    const float2 v = rp[stid];
    const float w0 = su[0][j], w1 = su[1][j], w2 = su[2][j];
    a0x += w0 * v.x; a0y += w0 * v.y;
    a1x += w1 * v.x; a1y += w1 * v.y;
    a2x += w2 * v.x; a2y += w2 * v.y;
    if (tail) {
      const float2 v2 = rp[128 + stid];
      c0x += w0 * v2.x; c0y += w0 * v2.y;
      c1x += w1 * v2.x; c1y += w1 * v2.y;
      c2x += w2 * v2.x; c2y += w2 * v2.y;
    }
  }

  float* Gp = Gred4 + (size_t)((b * 4 + (tc & 3)) * 3) * DD;
  const int d0 = 2 * stid;
  atomicAdd(&Gp[0 * DD + d0], a0x); atomicAdd(&Gp[0 * DD + d0 + 1], a0y);
  atomicAdd(&Gp[1 * DD + d0], a1x); atomicAdd(&Gp[1 * DD + d0 + 1], a1y);
  atomicAdd(&Gp[2 * DD + d0], a2x); atomicAdd(&Gp[2 * DD + d0 + 1], a2y);
  if (tail) {
    const int d1 = 2 * (128 + stid);
    atomicAdd(&Gp[0 * DD + d1], c0x); atomicAdd(&Gp[0 * DD + d1 + 1], c0y);
    atomicAdd(&Gp[1 * DD + d1], c1x); atomicAdd(&Gp[1 * DD + d1 + 1], c1y);
    atomicAdd(&Gp[2 * DD + d1], c2x); atomicAdd(&Gp[2 * DD + d1 + 1], c2y);
  }
}

// ---------------------------------------------------------------------------
// Kernel 2: sim GEMV — one wave per output o = b*384 + j  (24576 outputs).
// Grid 6144 x 256. Sums the 4 slices inline (Gred4 921 KB + conv_w 154 KB,
// both L2-resident; 15 coalesced float2 loads per wave), 6-shfl reduce.
//   hT[b*384+j] = <conv_w[cp], sum_s Gred4[b][s][kk]> + conv_b[cp]*Sk + bk
// ---------------------------------------------------------------------------
__global__ __launch_bounds__(256) void k_sim(
    const float* __restrict__ Gred4, const float* __restrict__ conv_w,
    const float* __restrict__ conv_b, const float* __restrict__ skbk,
    float* __restrict__ hT) {
  const int o = blockIdx.x * 4 + (threadIdx.x >> 6);
  const int lane = threadIdx.x & 63;
  const int b = o / 384;
  const int j = o - b * 384;
  const int kk = j >> 7;
  const int cp = j & 127;

  const float2* cwp = (const float2*)(conv_w + cp * DD);  // 150 float2
  const float2* g0 = (const float2*)(Gred4 + (size_t)b * 4 * 3 * DD + kk * DD);
  // slices at +450 float2 (= 900 floats = 3*DD)

  float acc = 0.f;
#pragma unroll
  for (int seg = 0; seg < 3; ++seg) {
    const int idx = lane + seg * 64;
    if (seg < 2 || lane < 22) {
      const float2 v = cwp[idx];
      const float2 ga = g0[idx];
      const float2 gb = g0[450 + idx];
      const float2 gc = g0[900 + idx];
      const float2 gd = g0[1350 + idx];
      const float gx = (ga.x + gb.x) + (gc.x + gd.x);
      const float gy = (ga.y + gb.y) + (gc.y + gd.y);
      acc += v.x * gx + v.y * gy;
    }
  }
#pragma unroll
  for (int off = 32; off >= 1; off >>= 1) acc += __shfl_down(acc, off, 64);
  if (lane == 0) {
    hT[b * (3 * CC) + j] = acc + conv_b[cp] * skbk[kk] + skbk[3 + kk];
  }
}

// ---------------------------------------------------------------------------
// Kernel 3: final FC — one wave per output o = b*128 + c  (8192 outputs).
// Grid 2048 x 256. hT is [b][j]-major and fcw rows are j-major, so both
// reads coalesce across lanes (6 segments of 64).
//   out[b,c] = sum_j fcw[c,j]*hT[b,j] + fcb[c]
// ---------------------------------------------------------------------------
__global__ __launch_bounds__(256) void k_fc(
    const float* __restrict__ hT, const float* __restrict__ fcw,
    const float* __restrict__ fcb, float* __restrict__ out) {
  const int o = blockIdx.x * 4 + (threadIdx.x >> 6);
  const int lane = threadIdx.x & 63;
  const int b = o >> 7;
  const int c = o & 127;

  const float* fr = fcw + c * (3 * CC);
  const float* hr = hT + b * (3 * CC);
  float acc = 0.f;
#pragma unroll
  for (int s = 0; s < 6; ++s) acc += fr[s * 64 + lane] * hr[s * 64 + lane];
#pragma unroll
  for (int off = 32; off >= 1; off >>= 1) acc += __shfl_down(acc, off, 64);
  if (lane == 0) out[b * CC + c] = acc + fcb[c];
}

// ---------------------------------------------------------------------------
extern "C" void kernel_launch(void* const* d_in, const int* in_sizes, int n_in,
                              void* d_out, int out_size, void* d_ws,
                              size_t ws_size, hipStream_t stream) {
  const int* x = (const int*)d_in[0];
  const float* embed = (const float*)d_in[1];
  const float* conv_w = (const float*)d_in[2];
  const float* conv_b = (const float*)d_in[3];
  const float* fc3w = (const float*)d_in[4];
  const float* fc3b = (const float*)d_in[5];
  const float* fc4w = (const float*)d_in[6];
  const float* fc4b = (const float*)d_in[7];
  const float* fc5w = (const float*)d_in[8];
  const float* fc5b = (const float*)d_in[9];
  const float* fcw = (const float*)d_in[10];
  const float* fcb = (const float*)d_in[11];

  float* Gred4 = (float*)d_ws;
  float* hT = (float*)d_ws + OFF_HT;
  float* skbk = (float*)d_ws + OFF_SKBK;

  hipMemsetAsync(Gred4, 0, (size_t)BB * 4 * 3 * DD * sizeof(float), stream);
  k_gather<<<dim3(2048 + 3), dim3(256), 0, stream>>>(
      x, embed, fc3w, fc3b, fc4w, fc4b, fc5w, fc5b, Gred4, skbk);
  k_sim<<<dim3(6144), dim3(256), 0, stream>>>(Gred4, conv_w, conv_b, skbk, hT);
  k_fc<<<dim3(2048), dim3(256), 0, stream>>>(hT, fcw, fcb, (float*)d_out);
}

// Round 7
// 129.719 us; speedup vs baseline: 1.2496x; 1.2496x over previous
//
#include <hip/hip_runtime.h>
#include <stdint.h>

#define BB 64
#define LL 512
#define DD 300
#define CC 128

// ws layout (floats):
//   Gpart : [64][32][3][300] = 1,843,200   (non-atomic per-block partials)
//   Gred  : [64][3][300]     =    57,600   (float4 view: [64][225])
//   hT    : [64][384]        =    24,576   (b-major so k_fc reads coalesce)
//   skbk  : [8]  (Sk[0..2], bk[0..2])
#define OFF_GRED (BB * 32 * 3 * DD)
#define OFF_HT   (OFF_GRED + BB * 3 * DD)
#define OFF_SKBK (OFF_HT + BB * 3 * CC)

// ---------------------------------------------------------------------------
// Kernel 1: weighted embedding gather with MANUAL 8-deep load batching.
//   Gpart[b][p][kk][d] = sum_{t in chunk p} u_k[t] * embed[x[b,t]][d]
// u_k[t] = sum of wk[l] over valid windows covering token t (<=5 terms).
// Grid 1024 x 256 (64 b x 16 tc, 32 tokens per block, 16 per half-block).
// Each half-block's thread owns float2 slots {stid, 128+stid (tail, <150)}.
// The 8 row loads per batch are issued into register arrays BEFORE any FMA
// (R6 showed VGPR=32: compiler wasn't pipelining; this forces 16 loads in
// flight per wave to hide the ~900-cyc HBM latency — L3 is cold each call
// because the harness's 268 MB ws poison fill evicts it).
// ---------------------------------------------------------------------------
__global__ __launch_bounds__(256) void k_gather(
    const int* __restrict__ x, const float* __restrict__ embed,
    const float* __restrict__ w3, const float* __restrict__ w4,
    const float* __restrict__ w5, float* __restrict__ Gpart) {
  const int b = blockIdx.x >> 4;
  const int tc = blockIdx.x & 15;
  const int tid = threadIdx.x;
  const int sub = tid >> 7;    // half-block: 16 tokens each
  const int stid = tid & 127;  // float2 slot

  __shared__ int sx[32];
  __shared__ float su[3][32];

  if (tid < 32) {
    const int t = tc * 32 + tid;
    sx[tid] = x[b * LL + t];
    const float* ws[3] = {w3, w4, w5};
#pragma unroll
    for (int kk = 0; kk < 3; ++kk) {
      const int k = kk + 3;
      int lo = t - k + 1; if (lo < 0) lo = 0;
      int hi = t; const int lim = LL - k - 1; if (hi > lim) hi = lim;
      float s = 0.f;
      for (int l = lo; l <= hi; ++l) s += ws[kk][l];
      su[kk][tid] = s;
    }
  }
  __syncthreads();

  float a0x = 0.f, a0y = 0.f, a1x = 0.f, a1y = 0.f, a2x = 0.f, a2y = 0.f;
  float c0x = 0.f, c0y = 0.f, c1x = 0.f, c1y = 0.f, c2x = 0.f, c2y = 0.f;
  const bool tail = stid < (DD / 2 - 128);  // slots 128..149 -> 22 lanes

#pragma unroll
  for (int half = 0; half < 2; ++half) {
    const int base = sub * 16 + half * 8;
    float2 v[8], u[8];
#pragma unroll
    for (int i = 0; i < 8; ++i) {
      const float2* rp = (const float2*)(embed + (size_t)sx[base + i] * DD);
      v[i] = rp[stid];
    }
    if (tail) {
#pragma unroll
      for (int i = 0; i < 8; ++i) {
        const float2* rp = (const float2*)(embed + (size_t)sx[base + i] * DD);
        u[i] = rp[128 + stid];
      }
    }
#pragma unroll
    for (int i = 0; i < 8; ++i) {
      const int j = base + i;
      const float w0 = su[0][j], w1 = su[1][j], w2 = su[2][j];
      a0x += w0 * v[i].x; a0y += w0 * v[i].y;
      a1x += w1 * v[i].x; a1y += w1 * v[i].y;
      a2x += w2 * v[i].x; a2y += w2 * v[i].y;
      if (tail) {
        c0x += w0 * u[i].x; c0y += w0 * u[i].y;
        c1x += w1 * u[i].x; c1y += w1 * u[i].y;
        c2x += w2 * u[i].x; c2y += w2 * u[i].y;
      }
    }
  }

  const int p = tc * 2 + sub;  // 0..31
  float* Gp = Gpart + (size_t)(b * 32 + p) * (3 * DD);
  const int d0 = 2 * stid;
  Gp[0 * DD + d0] = a0x; Gp[0 * DD + d0 + 1] = a0y;
  Gp[1 * DD + d0] = a1x; Gp[1 * DD + d0 + 1] = a1y;
  Gp[2 * DD + d0] = a2x; Gp[2 * DD + d0 + 1] = a2y;
  if (tail) {
    const int d1 = 2 * (128 + stid);
    Gp[0 * DD + d1] = c0x; Gp[0 * DD + d1 + 1] = c0y;
    Gp[1 * DD + d1] = c1x; Gp[1 * DD + d1 + 1] = c1y;
    Gp[2 * DD + d1] = c2x; Gp[2 * DD + d1 + 1] = c2y;
  }
}

// ---------------------------------------------------------------------------
// Kernel 2: parallel partial reduction. 14400 float4 outputs x 4 threads
// each (8 partials per thread, 2-step shfl combine) = 57600 threads in
// blocks 0..224. Blocks 225..227 compute Sk[kk] = sum(wk), stash bk[kk].
// ---------------------------------------------------------------------------
__global__ __launch_bounds__(256) void k_reduce(
    const float* __restrict__ Gpart,
    const float* __restrict__ w3, const float* __restrict__ b3,
    const float* __restrict__ w4, const float* __restrict__ b4,
    const float* __restrict__ w5, const float* __restrict__ b5,
    float* __restrict__ Gred, float* __restrict__ skbk) {
  const int blk = blockIdx.x;
  const int tid = threadIdx.x;

  if (blk < 225) {
    const int gid = blk * 256 + tid;  // 57600
    const int out = gid >> 2;         // float4 output id, < 14400
    const int r = gid & 3;            // partial-group 0..3
    const int b = out / 225;
    const int q = out - b * 225;
    const float4* gp =
        (const float4*)Gpart + (size_t)b * 32 * 225 + (size_t)r * 8 * 225 + q;
    float4 s = gp[0];
#pragma unroll
    for (int p = 1; p < 8; ++p) {
      const float4 v = gp[(size_t)p * 225];
      s.x += v.x; s.y += v.y; s.z += v.z; s.w += v.w;
    }
    // combine the 4 r-groups (adjacent lanes) via shfl
#pragma unroll
    for (int off = 1; off <= 2; off <<= 1) {
      s.x += __shfl_down(s.x, off, 64);
      s.y += __shfl_down(s.y, off, 64);
      s.z += __shfl_down(s.z, off, 64);
      s.w += __shfl_down(s.w, off, 64);
    }
    if (r == 0) ((float4*)Gred)[out] = s;
  } else {
    __shared__ float red[256];
    const int kk = blk - 225;
    const float* wk = (kk == 0) ? w3 : ((kk == 1) ? w4 : w5);
    const float* bk = (kk == 0) ? b3 : ((kk == 1) ? b4 : b5);
    const int len = LL - (kk + 3);
    float s = (tid < len) ? wk[tid] : 0.f;
    if (tid + 256 < len) s += wk[tid + 256];
    red[tid] = s;
    __syncthreads();
    for (int off = 128; off >= 1; off >>= 1) {
      if (tid < off) red[tid] += red[tid + off];
      __syncthreads();
    }
    if (tid == 0) { skbk[kk] = red[0]; skbk[3 + kk] = bk[0]; }
  }
}

// ---------------------------------------------------------------------------
// Kernel 3: sim GEMV — one wave per output o = b*384 + j  (24576 outputs).
// Grid 6144 x 256. conv_w (154 KB) and Gred (230 KB) are L2-resident; all
// reads coalesced per wave; 6-shfl reduce.
//   hT[b*384 + j] = <conv_w[cp], Gred[b][kk]> + conv_b[cp]*Sk[kk] + bk[kk]
// ---------------------------------------------------------------------------
__global__ __launch_bounds__(256) void k_sim(
    const float* __restrict__ Gred, const float* __restrict__ conv_w,
    const float* __restrict__ conv_b, const float* __restrict__ skbk,
    float* __restrict__ hT) {
  const int o = blockIdx.x * 4 + (threadIdx.x >> 6);
  const int lane = threadIdx.x & 63;
  const int b = o / 384;
  const int j = o - b * 384;
  const int kk = j >> 7;
  const int cp = j & 127;

  const float2* cwp = (const float2*)(conv_w + cp * DD);         // 150 float2
  const float2* g2 = (const float2*)(Gred + (b * 3 + kk) * DD);  // 150 float2

  float acc;
  {
    const float2 v = cwp[lane];
    const float2 g = g2[lane];
    acc = v.x * g.x + v.y * g.y;
  }
  {
    const float2 v = cwp[lane + 64];
    const float2 g = g2[lane + 64];
    acc += v.x * g.x + v.y * g.y;
  }
  if (lane < 22) {
    const float2 v = cwp[lane + 128];
    const float2 g = g2[lane + 128];
    acc += v.x * g.x + v.y * g.y;
  }
#pragma unroll
  for (int off = 32; off >= 1; off >>= 1) acc += __shfl_down(acc, off, 64);
  if (lane == 0) {
    hT[b * (3 * CC) + j] = acc + conv_b[cp] * skbk[kk] + skbk[3 + kk];
  }
}

// ---------------------------------------------------------------------------
// Kernel 4: final FC — one wave per output o = b*128 + c  (8192 outputs).
// Grid 2048 x 256. hT is [b][j]-major and fcw rows are j-major, so both
// reads coalesce across lanes (6 segments of 64).
//   out[b,c] = sum_j fcw[c,j]*hT[b,j] + fcb[c]
// ---------------------------------------------------------------------------
__global__ __launch_bounds__(256) void k_fc(
    const float* __restrict__ hT, const float* __restrict__ fcw,
    const float* __restrict__ fcb, float* __restrict__ out) {
  const int o = blockIdx.x * 4 + (threadIdx.x >> 6);
  const int lane = threadIdx.x & 63;
  const int b = o >> 7;
  const int c = o & 127;

  const float* fr = fcw + c * (3 * CC);
  const float* hr = hT + b * (3 * CC);
  float acc = 0.f;
#pragma unroll
  for (int s = 0; s < 6; ++s) acc += fr[s * 64 + lane] * hr[s * 64 + lane];
#pragma unroll
  for (int off = 32; off >= 1; off >>= 1) acc += __shfl_down(acc, off, 64);
  if (lane == 0) out[b * CC + c] = acc + fcb[c];
}

// ---------------------------------------------------------------------------
extern "C" void kernel_launch(void* const* d_in, const int* in_sizes, int n_in,
                              void* d_out, int out_size, void* d_ws,
                              size_t ws_size, hipStream_t stream) {
  const int* x = (const int*)d_in[0];
  const float* embed = (const float*)d_in[1];
  const float* conv_w = (const float*)d_in[2];
  const float* conv_b = (const float*)d_in[3];
  const float* fc3w = (const float*)d_in[4];
  const float* fc3b = (const float*)d_in[5];
  const float* fc4w = (const float*)d_in[6];
  const float* fc4b = (const float*)d_in[7];
  const float* fc5w = (const float*)d_in[8];
  const float* fc5b = (const float*)d_in[9];
  const float* fcw = (const float*)d_in[10];
  const float* fcb = (const float*)d_in[11];

  float* Gpart = (float*)d_ws;
  float* Gred = (float*)d_ws + OFF_GRED;
  float* hT = (float*)d_ws + OFF_HT;
  float* skbk = (float*)d_ws + OFF_SKBK;

  k_gather<<<dim3(BB * 16), dim3(256), 0, stream>>>(x, embed, fc3w, fc4w,
                                                    fc5w, Gpart);
  k_reduce<<<dim3(228), dim3(256), 0, stream>>>(Gpart, fc3w, fc3b, fc4w, fc4b,
                                                fc5w, fc5b, Gred, skbk);
  k_sim<<<dim3(6144), dim3(256), 0, stream>>>(Gred, conv_w, conv_b, skbk, hT);
  k_fc<<<dim3(2048), dim3(256), 0, stream>>>(hT, fcw, fcb, (float*)d_out);
}